// Round 9
// baseline (379.461 us; speedup 1.0000x reference)
//
#include <hip/hip_runtime.h>
#include <math.h>

#define N_ 128
#define I_ 256
#define O_ 256
#define P_ 16
#define OT 4      // o's per block (site kernel)
#define IT 8      // i's per block (site kernel)
#define ICH 4     // fallback kernel chunking
#define SQRT_2PI 2.5066282746310002f
#define INV_SQRT_2PI 0.3989422804014327f

// ---- Packed record layout v3 (R23: M in f16, w/z/sc in f32) ----
// Per pair: 8 units of 64B (512B), interleaved per 16-pair group:
//   unit j of pair q at float offset (q>>4)*2048 + j*256 + (q&15)*16
//   units 0..4 : 40 M-chunks as f16 RN (chunk = col m, rows 4c..4c+3 =
//                4 f16 = 2 u32; 2 chunks per float4, producer order)
//   unit 5 : z f32   unit 6 : w f32   unit 7 : l2, s2l f32 + pad
#define GF 2048                    // floats per 16-pair group
#define NEED_BYTES ((size_t)4096 * GF * 4)   // 33.6 MB

typedef float f2 __attribute__((ext_vector_type(2)));
typedef _Float16 h2 __attribute__((ext_vector_type(2)));

__device__ __forceinline__ float fast_tanh(float x) {
    const float e2 = __expf(2.0f * x);
    return 1.0f - 2.0f / (e2 + 1.0f);
}

// f32x2 -> packed f16x2 (round-nearest via scalar casts)
__device__ __forceinline__ uint32_t pkh(float a, float b) {
    h2 h;
    h.x = (_Float16)a;
    h.y = (_Float16)b;
    return __builtin_bit_cast(uint32_t, h);
}

// ============================ Kernel 1: pairs ==============================
// R27: LDS-resident triangle + ROLLED loops. The R0 serial kernel's fully
// unrolled body is ~32-40KB straight-line code >= L1I (32KB): every wave
// cold-streams it (issue floor ~4us vs measured ~88us; ~500 lines x 160cy
// matches). This version keeps the SAME algorithm but holds A in LDS
// (thread-private column As[slot][t]: 64 lanes x stride-64 floats -> 2-way
// bank aliasing = free) with rolled loops -> ~8KB code, I$-resident.
// Column-major triangular layout: col c base = 16c - c(c-1)/2, elem (r,c)
// at base + r - c. fp order of build/chol/inversion/tv/wv matches R0.
// Slots: A 0..135, dinv 136..151 (h->tv phase reuses), z 152..167 (x/tv).
#define SA 0
#define SD 136
#define SZ 152
__global__ __launch_bounds__(64, 1) void gp_pairs(
    const float* __restrict__ z_param, const float* __restrict__ h,
    const float* __restrict__ l_param, const float* __restrict__ s_param,
    const float* __restrict__ jitter_param, float* __restrict__ ws)
{
    __shared__ float As[168][64];   // 43,008 B -> 3 blocks/CU

    const int t = threadIdx.x;
    const int q = blockIdx.x * 64 + t;   // pair index = i*256 + o
    const int io = q;

    const float l   = __expf(l_param[io]) + 0.2f;
    const float s   = __expf(s_param[io]) + 0.1f;
    const float jit = __expf(jitter_param[io]) + 0.01f;
    const float l2 = l * l;
    const float ninv2l2 = -0.5f / l2;
    const float cQ = INV_SQRT_2PI / l;
    const float noise = jit * jit / (s * s * l * SQRT_2PI);
    const float s2l = s * s * l;

    float4* rb4 = (float4*)ws + (size_t)(q >> 4) * (GF / 4) + (size_t)(q & 15) * 4;

    // ---- load z, tanh, store unit 5, park in LDS ----
    {
        const float4* zp = (const float4*)(z_param + (size_t)io * P_);
        float4* zpo = rb4 + 5 * 64;
        #pragma unroll
        for (int cc = 0; cc < 4; ++cc) {
            float4 z4 = zp[cc];
            z4.x = fast_tanh(z4.x); z4.y = fast_tanh(z4.y);
            z4.z = fast_tanh(z4.z); z4.w = fast_tanh(z4.w);
            zpo[cc] = z4;
            As[SZ + 4*cc + 0][t] = z4.x; As[SZ + 4*cc + 1][t] = z4.y;
            As[SZ + 4*cc + 2][t] = z4.z; As[SZ + 4*cc + 3][t] = z4.w;
        }
    }

    // ---- A-build (column-major), rolled ----
    {
        int base = 0;
        #pragma unroll 1
        for (int c = 0; c < 16; ++c) {
            const float zc = As[SZ + c][t];
            As[SA + base][t] = cQ + noise;          // diag: exp(0)=1
            #pragma unroll 4
            for (int r = c + 1; r < 16; ++r) {
                const float d = As[SZ + r][t] - zc;
                As[SA + base + r - c][t] = cQ * __expf(d * d * ninv2l2);
            }
            base += 16 - c;
        }
    }

    // ---- Cholesky (right-looking), rolled ----
    {
        int bk = 0;
        #pragma unroll 1
        for (int k = 0; k < 16; ++k) {
            const float Lkk = sqrtf(As[SA + bk][t]);
            const float ik = 1.0f / Lkk;
            As[SD + k][t] = ik;
            As[SA + bk][t] = Lkk;
            #pragma unroll 4
            for (int r = k + 1; r < 16; ++r) As[SA + bk + r - k][t] *= ik;
            int bc = bk + 16 - k;
            #pragma unroll 1
            for (int c = k + 1; c < 16; ++c) {
                const float lck = As[SA + bk + c - k][t];
                #pragma unroll 4
                for (int r = c; r < 16; ++r)
                    As[SA + bc + r - c][t] -= As[SA + bk + r - k][t] * lck;
                bc += 16 - c;
            }
            bk += 16 - k;
        }
    }

    // ---- issue h load now; latency hides under inversion + pack ----
    float4 h4r[4];
    {
        const float4* hp = (const float4*)(h + (size_t)io * P_);
        h4r[0] = hp[0]; h4r[1] = hp[1]; h4r[2] = hp[2]; h4r[3] = hp[3];
    }

    // ---- in-place inversion A := M = L^-1 (row recurrence, R0 order) ----
    {
        int bj = 0;
        #pragma unroll 1
        for (int j = 0; j < 16; ++j) {
            const float dj = As[SD + j][t];
            #pragma unroll 1
            for (int r = j + 1; r < 16; ++r) {
                float acc = As[SA + bj + r - j][t] * dj;
                int bk3 = bj + 16 - j;
                #pragma unroll 4
                for (int k = j + 1; k < r; ++k) {
                    acc += As[SA + bk3 + r - k][t] * As[SA + bj + k - j][t];
                    bk3 += 16 - k;
                }
                As[SA + bj + r - j][t] = -As[SD + r][t] * acc;
            }
            As[SA + bj][t] = dj;
            bj += 16 - j;
        }
    }

    // ---- pack-store M chunks (f16), rolled; layout matches consumer ----
    {
        uint32_t u0 = 0, u1 = 0;
        int k = 0;
        int bm = 0;
        #pragma unroll 1
        for (int m = 0; m < 16; ++m) {
            #pragma unroll 1
            for (int c = (m >> 2); c < 4; ++c) {
                const int r0 = 4 * c;
                const float v0 = (r0     < m) ? 0.f : As[SA + bm + r0     - m][t];
                const float v1 = (r0 + 1 < m) ? 0.f : As[SA + bm + r0 + 1 - m][t];
                const float v2 = (r0 + 2 < m) ? 0.f : As[SA + bm + r0 + 2 - m][t];
                const float v3 = (r0 + 3 < m) ? 0.f : As[SA + bm + r0 + 3 - m][t];
                const uint32_t lo = pkh(v0, v1);
                const uint32_t hi = pkh(v2, v3);
                if ((k & 1) == 0) { u0 = lo; u1 = hi; }
                else {
                    const int f = k >> 1;
                    rb4[(f >> 2) * 64 + (f & 3)] = make_float4(
                        __uint_as_float(u0), __uint_as_float(u1),
                        __uint_as_float(lo), __uint_as_float(hi));
                }
                ++k;
            }
            bm += 16 - m;
        }
    }

    // ---- park h in SZ (z dead), tv in SD (dinv dead; M diag holds it) ----
    {
        #pragma unroll
        for (int cc = 0; cc < 4; ++cc) {
            As[SZ + 4*cc + 0][t] = h4r[cc].x; As[SZ + 4*cc + 1][t] = h4r[cc].y;
            As[SZ + 4*cc + 2][t] = h4r[cc].z; As[SZ + 4*cc + 3][t] = h4r[cc].w;
        }
        #pragma unroll 4
        for (int r = 0; r < 16; ++r) As[SD + r][t] = 0.f;
        int bc2 = 0;
        #pragma unroll 1
        for (int c = 0; c < 16; ++c) {
            const float hc = As[SZ + c][t];
            #pragma unroll 4
            for (int r = c; r < 16; ++r)
                As[SD + r][t] += As[SA + bc2 + r - c][t] * hc;
            bc2 += 16 - c;
        }
        // wv[c] = sum_r M[r][c] tv[r] -> overwrite SZ (h dead)
        int bc3 = 0;
        #pragma unroll 1
        for (int c = 0; c < 16; ++c) {
            float acc = 0.f;
            #pragma unroll 4
            for (int r = c; r < 16; ++r)
                acc += As[SA + bc3 + r - c][t] * As[SD + r][t];
            As[SZ + c][t] = acc;
            bc3 += 16 - c;
        }
        float4* wp = rb4 + 6 * 64;
        wp[0] = make_float4(As[SZ+ 0][t], As[SZ+ 1][t], As[SZ+ 2][t], As[SZ+ 3][t]);
        wp[1] = make_float4(As[SZ+ 4][t], As[SZ+ 5][t], As[SZ+ 6][t], As[SZ+ 7][t]);
        wp[2] = make_float4(As[SZ+ 8][t], As[SZ+ 9][t], As[SZ+10][t], As[SZ+11][t]);
        wp[3] = make_float4(As[SZ+12][t], As[SZ+13][t], As[SZ+14][t], As[SZ+15][t]);
        float4* sp = rb4 + 7 * 64;
        sp[0] = make_float4(l2, s2l, 0.f, 0.f);
    }
}

// ============================ Kernel 2: sites ==============================
// R23 (passed, 119us, VALU 53%): LDS-staged with f16-compressed M.
__global__ __launch_bounds__(256, 2) void gp_sites(
    const float* __restrict__ x_mean, const float* __restrict__ x_var,
    const float* __restrict__ ws, float* __restrict__ out)
{
    __shared__ float xm_s[N_][IT + 1];
    __shared__ float xv_s[N_][IT + 1];
    __shared__ __align__(16) float4 pbv[32 * 32];   // 32 records x 512B

    const int t = threadIdx.x;
    const int b = blockIdx.x;
    const int ot = b & 63;
    const int ir = b >> 6;
    const int i0 = ir * IT;

    // stage x slice
    {
        const int n = t >> 1, qq = t & 1;
        const float4 xm4 = *(const float4*)(x_mean + n * I_ + i0 + qq * 4);
        const float4 xv4 = *(const float4*)(x_var  + n * I_ + i0 + qq * 4);
        xm_s[n][qq*4+0] = xm4.x; xm_s[n][qq*4+1] = xm4.y;
        xm_s[n][qq*4+2] = xm4.z; xm_s[n][qq*4+3] = xm4.w;
        xv_s[n][qq*4+0] = xv4.x; xv_s[n][qq*4+1] = xv4.y;
        xv_s[n][qq*4+2] = xv4.z; xv_s[n][qq*4+3] = xv4.w;
    }

    // stage all 32 records (8 i x 4 o), coalesced: exactly 1024 float4s
    {
        const int g_hi = ot >> 2;
        const int s0x4 = (ot & 3) * 16;         // s0*4 in float4 units
        const float4* wsv = (const float4*)ws;
        #pragma unroll
        for (int k = 0; k < 4; ++k) {
            const int idx = t + k * 256;
            const int run = idx >> 4;           // 0..63 = i*8 + j
            const int f4i = idx & 15;           // ol*4 + c
            const int i = run >> 3;
            const int j = run & 7;
            const int gi = (i0 + i) * 16 + g_hi;
            const float4 v = wsv[(size_t)gi * (GF / 4) + j * 64 + s0x4 + f4i];
            pbv[(i * 4 + (f4i >> 2)) * 32 + j * 4 + (f4i & 3)] = v;
        }
    }
    __syncthreads();

    f2 am2 = {0.f, 0.f};
    f2 av2 = {IT * 0.1f, IT * 0.1f};   // GLOBAL_JITTER per i

    const int ol = t >> 6;   // o_local (0..3), one per wave
    const int ln = t & 63;   // sites n = ln and ln+64
    const int o  = ot * OT + ol;

    // chunk lk -> (column m, row-quad c), producer's order (R5-verified)
    constexpr int MKt[40] = {0,0,0,0, 1,1,1,1, 2,2,2,2, 3,3,3,3,
                             4,4,4, 5,5,5, 6,6,6, 7,7,7,
                             8,8, 9,9, 10,10, 11,11, 12, 13, 14, 15};
    constexpr int CKt[40] = {0,1,2,3, 0,1,2,3, 0,1,2,3, 0,1,2,3,
                             1,2,3, 1,2,3, 1,2,3, 1,2,3,
                             2,3, 2,3, 2,3, 2,3, 3, 3, 3, 3};

    for (int ii = 0; ii < IT; ++ii) {
        const float4* rp = &pbv[(ii * 4 + ol) * 32];

        const float4 scv = rp[28];
        const float l2  = scv.x;
        const float s2l = scv.y;
        const float t4v = SQRT_2PI * s2l;

        float zr[P_], wr[P_];
        #pragma unroll
        for (int c = 0; c < 4; ++c) {
            const float4 z4 = rp[20 + c], w4 = rp[24 + c];
            zr[4*c+0] = z4.x; zr[4*c+1] = z4.y; zr[4*c+2] = z4.z; zr[4*c+3] = z4.w;
            wr[4*c+0] = w4.x; wr[4*c+1] = w4.y; wr[4*c+2] = w4.z; wr[4*c+3] = w4.w;
        }

        f2 xm2, xv2;
        xm2.x = xm_s[ln][ii];       xm2.y = xm_s[ln + 64][ii];
        xv2.x = xv_s[ln][ii];       xv2.y = xv_s[ln + 64][ii];
        f2 v2 = xv2 + l2;
        f2 cc2, nh2;
        cc2.x = rsqrtf(v2.x) * INV_SQRT_2PI;
        cc2.y = rsqrtf(v2.y) * INV_SQRT_2PI;
        nh2.x = -0.5f / v2.x;
        nh2.y = -0.5f / v2.y;

        // ---- pass A: all 16 em2, dm2 (parity-split chains) ----
        f2 em2[P_];
        f2 dm2a = {0.f, 0.f}, dm2b = {0.f, 0.f};
        #pragma unroll
        for (int m = 0; m < P_; ++m) {
            f2 d2 = xm2 - zr[m];
            f2 tt = d2 * d2 * nh2;
            em2[m].x = __expf(tt.x);
            em2[m].y = __expf(tt.y);
            if (m & 1) dm2b += em2[m] * wr[m];
            else       dm2a += em2[m] * wr[m];
        }
        const f2 dm2 = dm2a + dm2b;

        // ---- pass B: 20 float4 reads = 40 f16 chunks ----
        f2 u2[P_];
        #pragma unroll
        for (int tt = 0; tt < 20; ++tt) {
            const float4 F = rp[tt];
            const h2 pa = __builtin_bit_cast(h2, F.x);
            const h2 pb = __builtin_bit_cast(h2, F.y);
            const h2 pc = __builtin_bit_cast(h2, F.z);
            const h2 pd = __builtin_bit_cast(h2, F.w);
            {   // chunk 2*tt : values pa.x pa.y pb.x pb.y
                const int lk = 2 * tt;
                const int m = MKt[lk], c = CKt[lk];
                const float v0 = (float)pa.x, v1 = (float)pa.y;
                const float v2c = (float)pb.x, v3 = (float)pb.y;
                if (lk < 4) {
                    u2[4*c+0] = v0  * em2[m];
                    u2[4*c+1] = v1  * em2[m];
                    u2[4*c+2] = v2c * em2[m];
                    u2[4*c+3] = v3  * em2[m];
                } else {
                    u2[4*c+0] += v0  * em2[m];
                    u2[4*c+1] += v1  * em2[m];
                    u2[4*c+2] += v2c * em2[m];
                    u2[4*c+3] += v3  * em2[m];
                }
            }
            {   // chunk 2*tt+1 : values pc.x pc.y pd.x pd.y
                const int lk = 2 * tt + 1;
                const int m = MKt[lk], c = CKt[lk];
                const float v0 = (float)pc.x, v1 = (float)pc.y;
                const float v2c = (float)pd.x, v3 = (float)pd.y;
                if (lk < 4) {
                    u2[4*c+0] = v0  * em2[m];
                    u2[4*c+1] = v1  * em2[m];
                    u2[4*c+2] = v2c * em2[m];
                    u2[4*c+3] = v3  * em2[m];
                } else {
                    u2[4*c+0] += v0  * em2[m];
                    u2[4*c+1] += v1  * em2[m];
                    u2[4*c+2] += v2c * em2[m];
                    u2[4*c+3] += v3  * em2[m];
                }
            }
        }

        f2 su2a = {0.f, 0.f}, su2b = {0.f, 0.f};
        #pragma unroll
        for (int r = 0; r < P_; r += 2) {
            su2a += u2[r] * u2[r];
            su2b += u2[r+1] * u2[r+1];
        }
        const f2 su2 = su2a + su2b;

        am2 += cc2 * dm2;
        f2 t32;
        t32.x = s2l * rsqrtf(l2 + 2.f * xv2.x);
        t32.y = s2l * rsqrtf(l2 + 2.f * xv2.y);
        av2 += t32 - t4v * (cc2 * cc2) * su2;
    }

    atomicAdd(out + ln * O_ + o,                  am2.x);
    atomicAdd(out + (ln + 64) * O_ + o,           am2.y);
    atomicAdd(out + N_ * O_ + ln * O_ + o,        av2.x);
    atomicAdd(out + N_ * O_ + (ln + 64) * O_ + o, av2.y);
}

// ===================== Fallback: R5 monolithic kernel ======================
#define LSTR 20
__global__ __launch_bounds__(256, 2) void gp_fused(
    const float* __restrict__ x_mean, const float* __restrict__ x_var,
    const float* __restrict__ z_param, const float* __restrict__ h,
    const float* __restrict__ l_param, const float* __restrict__ s_param,
    const float* __restrict__ jitter_param, float* __restrict__ out)
{
    __shared__ float xm_s[N_][IT + 1];
    __shared__ float xv_s[N_][IT + 1];
    __shared__ __align__(16) float LinvT[ICH][OT][P_][LSTR];
    __shared__ __align__(16) float zS[ICH][OT][P_];
    __shared__ __align__(16) float wS[ICH][OT][P_];
    __shared__ float scS[ICH][OT][2];

    const int t = threadIdx.x;
    const int b = blockIdx.x;
    const int ot = b & 63;
    const int ir = b >> 6;
    const int o_base = ot * OT;
    const int i0 = ir * IT;

    {
        const int n = t >> 1, q = t & 1;
        const float4 xm4 = *(const float4*)(x_mean + n * I_ + i0 + q * 4);
        const float4 xv4 = *(const float4*)(x_var  + n * I_ + i0 + q * 4);
        xm_s[n][q*4+0] = xm4.x; xm_s[n][q*4+1] = xm4.y;
        xm_s[n][q*4+2] = xm4.z; xm_s[n][q*4+3] = xm4.w;
        xv_s[n][q*4+0] = xv4.x; xv_s[n][q*4+1] = xv4.y;
        xv_s[n][q*4+2] = xv4.z; xv_s[n][q*4+3] = xv4.w;
    }
    __syncthreads();

    f2 am2 = {0.f, 0.f};
    f2 av2 = {IT * 0.1f, IT * 0.1f};

    const int ol = t >> 6;
    const int ln = t & 63;
    const int g2 = t >> 4;
    const int il = g2 >> 2;
    const int g  = g2 & 3;
    const int p  = t & 15;

    for (int ii4 = 0; ii4 < IT / ICH; ++ii4) {
        {
            const int i  = i0 + ii4 * ICH + il;
            const int o  = o_base + g;
            const int io = i * O_ + o;
            const float l   = expf(l_param[io]) + 0.2f;
            const float s   = expf(s_param[io]) + 0.1f;
            const float jit = expf(jitter_param[io]) + 0.01f;
            const float l2 = l * l;
            const float inv2l2 = 0.5f / l2;
            const float cQ = INV_SQRT_2PI / l;
            const float noise = jit * jit / (s * s * l * SQRT_2PI);
            const float zp = tanhf(z_param[io * P_ + p]);

            float a[P_];
            #pragma unroll
            for (int c = 0; c < P_; ++c) {
                const float zc = __shfl(zp, c, P_);
                const float d = zp - zc;
                a[c] = cQ * __expf(-d * d * inv2l2) + ((c == p) ? noise : 0.0f);
            }
            #pragma unroll
            for (int k = 0; k < P_; ++k) {
                const float akk = __shfl(a[k], k, P_);
                const float lkk = sqrtf(akk);
                const float inv_lkk = 1.0f / lkk;
                if (p == k)      a[k] = lkk;
                else if (p > k)  a[k] *= inv_lkk;
                const float lrk = a[k];
                #pragma unroll
                for (int c = k + 1; c < P_; ++c) {
                    const float lck = __shfl(a[k], c, P_);
                    if (p >= c) a[c] -= lrk * lck;
                }
            }
            float x[P_];
            #pragma unroll
            for (int r = 0; r < P_; ++r) {
                const float lrr = __shfl(a[r], r, P_);
                float acc = (r == p) ? 1.0f : 0.0f;
                #pragma unroll
                for (int m = 0; m < r; ++m) {
                    const float lrm = __shfl(a[m], r, P_);
                    acc -= lrm * x[m];
                }
                x[r] = acc / lrr;
            }
            const float hc = h[io * P_ + p];
            float y[P_];
            #pragma unroll
            for (int r = 0; r < P_; ++r) y[r] = x[r] * hc;
            #pragma unroll
            for (int off = 8; off >= 1; off >>= 1) {
                #pragma unroll
                for (int r = 0; r < P_; ++r) y[r] += __shfl_xor(y[r], off, P_);
            }
            float wc = 0.f;
            #pragma unroll
            for (int r = 0; r < P_; ++r) wc += x[r] * y[r];

            float4* dst = (float4*)&LinvT[il][g][p][0];
            dst[0] = make_float4(x[ 0], x[ 1], x[ 2], x[ 3]);
            dst[1] = make_float4(x[ 4], x[ 5], x[ 6], x[ 7]);
            dst[2] = make_float4(x[ 8], x[ 9], x[10], x[11]);
            dst[3] = make_float4(x[12], x[13], x[14], x[15]);
            zS[il][g][p] = zp;
            wS[il][g][p] = wc;
            if (p == 0) { scS[il][g][0] = l2; scS[il][g][1] = s * s * l; }
        }
        __syncthreads();

        #pragma unroll
        for (int il2 = 0; il2 < ICH; ++il2) {
            const int iiA = ii4 * ICH + il2;
            const float l2  = scS[il2][ol][0];
            const float s2l = scS[il2][ol][1];
            const float t4v = SQRT_2PI * s2l;
            float zr[P_], wr[P_];
            {
                const float4* zp4 = (const float4*)&zS[il2][ol][0];
                const float4* wp4 = (const float4*)&wS[il2][ol][0];
                #pragma unroll
                for (int c = 0; c < 4; ++c) {
                    const float4 z4 = zp4[c], w4 = wp4[c];
                    zr[4*c+0] = z4.x; zr[4*c+1] = z4.y; zr[4*c+2] = z4.z; zr[4*c+3] = z4.w;
                    wr[4*c+0] = w4.x; wr[4*c+1] = w4.y; wr[4*c+2] = w4.z; wr[4*c+3] = w4.w;
                }
            }
            f2 xm2, xv2;
            xm2.x = xm_s[ln][iiA];       xm2.y = xm_s[ln + 64][iiA];
            xv2.x = xv_s[ln][iiA];       xv2.y = xv_s[ln + 64][iiA];
            f2 v2 = xv2 + l2;
            f2 cc2, nh2;
            cc2.x = rsqrtf(v2.x) * INV_SQRT_2PI;
            cc2.y = rsqrtf(v2.y) * INV_SQRT_2PI;
            nh2.x = -0.5f / v2.x;
            nh2.y = -0.5f / v2.y;
            f2 dm2 = {0.f, 0.f};
            f2 u2[P_];
            #pragma unroll
            for (int m = 0; m < P_; ++m) {
                f2 d2 = xm2 - zr[m];
                f2 tt = d2 * d2 * nh2;
                f2 em2;
                em2.x = __expf(tt.x);
                em2.y = __expf(tt.y);
                dm2 += em2 * wr[m];
                const int c0 = m >> 2;
                #pragma unroll
                for (int c = 0; c < 4; ++c) {
                    if (c < c0) continue;
                    const float4 L4 = *(const float4*)&LinvT[il2][ol][m][4*c];
                    if (m == 0) {
                        u2[4*c+0] = L4.x * em2;
                        u2[4*c+1] = L4.y * em2;
                        u2[4*c+2] = L4.z * em2;
                        u2[4*c+3] = L4.w * em2;
                    } else {
                        u2[4*c+0] += L4.x * em2;
                        u2[4*c+1] += L4.y * em2;
                        u2[4*c+2] += L4.z * em2;
                        u2[4*c+3] += L4.w * em2;
                    }
                }
            }
            f2 su2 = {0.f, 0.f};
            #pragma unroll
            for (int r = 0; r < P_; ++r) su2 += u2[r] * u2[r];
            am2 += cc2 * dm2;
            f2 t32;
            t32.x = s2l * rsqrtf(l2 + 2.f * xv2.x);
            t32.y = s2l * rsqrtf(l2 + 2.f * xv2.y);
            av2 += t32 - t4v * (cc2 * cc2) * su2;
        }
        __syncthreads();
    }

    const int o = o_base + ol;
    atomicAdd(out + ln * O_ + o,                  am2.x);
    atomicAdd(out + (ln + 64) * O_ + o,           am2.y);
    atomicAdd(out + N_ * O_ + ln * O_ + o,        av2.x);
    atomicAdd(out + N_ * O_ + (ln + 64) * O_ + o, av2.y);
}

extern "C" void kernel_launch(void* const* d_in, const int* in_sizes, int n_in,
                              void* d_out, int out_size, void* d_ws, size_t ws_size,
                              hipStream_t stream) {
    const float* x_mean = (const float*)d_in[0];
    const float* x_var  = (const float*)d_in[1];
    const float* z_param = (const float*)d_in[2];
    const float* h       = (const float*)d_in[3];
    const float* l_param = (const float*)d_in[4];
    const float* s_param = (const float*)d_in[5];
    const float* jitter_param = (const float*)d_in[6];
    float* out = (float*)d_out;

    hipMemsetAsync(d_out, 0, (size_t)out_size * sizeof(float), stream);
    if (ws_size >= NEED_BYTES) {
        gp_pairs<<<dim3(1024), dim3(64), 0, stream>>>(
            z_param, h, l_param, s_param, jitter_param, (float*)d_ws);
        gp_sites<<<dim3(2048), dim3(256), 0, stream>>>(
            x_mean, x_var, (const float*)d_ws, out);
    } else {
        gp_fused<<<dim3(2048), dim3(256), 0, stream>>>(
            x_mean, x_var, z_param, h, l_param, s_param, jitter_param, out);
    }
}

// Round 11
// 239.825 us; speedup vs baseline: 1.5822x; 1.5822x over previous
//
#include <hip/hip_runtime.h>
#include <math.h>

#define N_ 128
#define I_ 256
#define O_ 256
#define P_ 16
#define OT 4      // o's per block
#define IT 8      // i's per block
#define SQRT_2PI 2.5066282746310002f
#define INV_SQRT_2PI 0.3989422804014327f

// ---- In-LDS record format (R23 v3, stride-padded) ----
// Record ridx = i_local*4 + o_local, base float4 = ridx*33 (33 = pad stride:
// 4 concurrent groups/wave write 4 consecutive records; 132-u32 stride
// spreads same-slot writes across banks).
//   float4 0..19 : 40 M-chunks f16 RN (chunk lk = col m, rows 4c..4c+3,
//                  2 u32; ordering m asc, c = (m>>2)..3)
//   float4 20..23: z f32   24..27: w f32   28: l2, s2l f32
#define RSTR 33

typedef float f2 __attribute__((ext_vector_type(2)));
typedef _Float16 h2 __attribute__((ext_vector_type(2)));

__device__ __forceinline__ float fast_tanh(float x) {
    const float e2 = __expf(2.0f * x);
    return 1.0f - 2.0f / (e2 + 1.0f);
}

__device__ __forceinline__ uint32_t pkh(float a, float b) {
    h2 hh;
    hh.x = (_Float16)a;
    hh.y = (_Float16)b;
    return __builtin_bit_cast(uint32_t, hh);
}

// ============================ Fused kernel =================================
// R29 (resubmit after infra failure): single kernel. Rationale: each record
// (i,o) is consumed by EXACTLY ONE block (ir=i/8, ot=o/4) -> the two-kernel
// split had zero reuse and cost an HBM round-trip + a launch boundary + an
// 88us pairs kernel that is structurally 1 wave/SIMD (1024 waves on 1024
// SIMDs; R9 counters: VALUBusy 6.9% = pure exposed latency). Producer phase
// = the R5-monolithic 16-lane shuffle Cholesky (proven), writing R23's f16
// record format (proven) into LDS; consumer = R23 verbatim. Producer DS
// work overlaps consumer VALU work across the 2 resident blocks/CU.
__global__ __launch_bounds__(256, 2) void gp_all(
    const float* __restrict__ x_mean, const float* __restrict__ x_var,
    const float* __restrict__ z_param, const float* __restrict__ h,
    const float* __restrict__ l_param, const float* __restrict__ s_param,
    const float* __restrict__ jitter_param, float* __restrict__ out)
{
    __shared__ float xm_s[N_][IT + 1];
    __shared__ float xv_s[N_][IT + 1];
    __shared__ __align__(16) float4 pbv[32 * RSTR];   // 16,896 B

    const int t = threadIdx.x;
    const int b = blockIdx.x;
    const int ot = b & 63;
    const int ir = b >> 6;
    const int i0 = ir * IT;
    const int o_base = ot * OT;

    // ---- stage x slice (8 i's x 128 n) ----
    {
        const int n = t >> 1, qq = t & 1;
        const float4 xm4 = *(const float4*)(x_mean + n * I_ + i0 + qq * 4);
        const float4 xv4 = *(const float4*)(x_var  + n * I_ + i0 + qq * 4);
        xm_s[n][qq*4+0] = xm4.x; xm_s[n][qq*4+1] = xm4.y;
        xm_s[n][qq*4+2] = xm4.z; xm_s[n][qq*4+3] = xm4.w;
        xv_s[n][qq*4+0] = xv4.x; xv_s[n][qq*4+1] = xv4.y;
        xv_s[n][qq*4+2] = xv4.z; xv_s[n][qq*4+3] = xv4.w;
    }

    // ---- producer: 2 rounds x 16 pairs, 16 lanes per pair ----
    {
        const int g2 = t >> 4;       // group 0..15
        const int il = g2 >> 2;      // i sub-index 0..3
        const int gg = g2 & 3;       // o_local 0..3
        const int p  = t & 15;       // lane within group
        const int o  = o_base + gg;

        #pragma unroll 1
        for (int rnd = 0; rnd < 2; ++rnd) {
            const int i  = i0 + rnd * 4 + il;
            const int io = i * O_ + o;
            const float l   = __expf(l_param[io]) + 0.2f;
            const float s   = __expf(s_param[io]) + 0.1f;
            const float jit = __expf(jitter_param[io]) + 0.01f;
            const float l2 = l * l;
            const float inv2l2 = 0.5f / l2;
            const float cQ = INV_SQRT_2PI / l;
            const float noise = jit * jit / (s * s * l * SQRT_2PI);
            const float zp = fast_tanh(z_param[(size_t)io * P_ + p]);

            // A row p across a[0..15]
            float a[P_];
            #pragma unroll
            for (int c = 0; c < P_; ++c) {
                const float zc = __shfl(zp, c, P_);
                const float d = zp - zc;
                a[c] = cQ * __expf(-d * d * inv2l2) + ((c == p) ? noise : 0.0f);
            }
            // Cholesky: a[c] -> L[p][c] (c <= p)
            #pragma unroll
            for (int k = 0; k < P_; ++k) {
                const float akk = __shfl(a[k], k, P_);
                const float lkk = sqrtf(akk);
                const float inv_lkk = 1.0f / lkk;
                if (p == k)      a[k] = lkk;
                else if (p > k)  a[k] *= inv_lkk;
                const float lrk = a[k];
                #pragma unroll
                for (int c = k + 1; c < P_; ++c) {
                    const float lck = __shfl(a[k], c, P_);
                    if (p >= c) a[c] -= lrk * lck;
                }
            }
            // forward substitution: x[r] = M[r][p] (exactly 0 for r < p)
            float x[P_];
            #pragma unroll
            for (int r = 0; r < P_; ++r) {
                const float lrr = __shfl(a[r], r, P_);
                float acc = (r == p) ? 1.0f : 0.0f;
                #pragma unroll
                for (int m = 0; m < r; ++m) {
                    const float lrm = __shfl(a[m], r, P_);
                    acc -= lrm * x[m];
                }
                x[r] = acc / lrr;
            }
            // w[p] = sum_r M[r][p] * (M h)[r]
            const float hc = h[(size_t)io * P_ + p];
            float y[P_];
            #pragma unroll
            for (int r = 0; r < P_; ++r) y[r] = x[r] * hc;
            #pragma unroll
            for (int off = 8; off >= 1; off >>= 1) {
                #pragma unroll
                for (int r = 0; r < P_; ++r) y[r] += __shfl_xor(y[r], off, P_);
            }
            float wc = 0.f;
            #pragma unroll
            for (int r = 0; r < P_; ++r) wc += x[r] * y[r];

            // ---- write record into LDS (v3 format) ----
            const int ridx = (rnd * 4 + il) * 4 + gg;
            uint32_t* ru = (uint32_t*)&pbv[ridx * RSTR];
            const int a4 = p >> 2;
            const int lk0 = 4 * p - 2 * a4 * (a4 - 1) - a4 * (p & 3);
            #pragma unroll
            for (int c = 0; c < 4; ++c) {
                if (c >= a4) {
                    const int lk = lk0 + (c - a4);
                    ru[2 * lk]     = pkh(x[4*c],   x[4*c+1]);
                    ru[2 * lk + 1] = pkh(x[4*c+2], x[4*c+3]);
                }
            }
            float* rf = (float*)ru;
            rf[80 + p] = zp;
            rf[96 + p] = wc;
            if (p == 0) { rf[112] = l2; rf[113] = s * s * l; }
        }
    }
    __syncthreads();

    // ---- consumer: R23 verbatim (stride RSTR) ----
    f2 am2 = {0.f, 0.f};
    f2 av2 = {IT * 0.1f, IT * 0.1f};   // GLOBAL_JITTER per i

    const int ol = t >> 6;   // o_local (0..3), one per wave
    const int ln = t & 63;   // sites n = ln and ln+64
    const int o  = ot * OT + ol;

    // chunk lk -> (column m, row-quad c), producer's order
    constexpr int MKt[40] = {0,0,0,0, 1,1,1,1, 2,2,2,2, 3,3,3,3,
                             4,4,4, 5,5,5, 6,6,6, 7,7,7,
                             8,8, 9,9, 10,10, 11,11, 12, 13, 14, 15};
    constexpr int CKt[40] = {0,1,2,3, 0,1,2,3, 0,1,2,3, 0,1,2,3,
                             1,2,3, 1,2,3, 1,2,3, 1,2,3,
                             2,3, 2,3, 2,3, 2,3, 3, 3, 3, 3};

    for (int ii = 0; ii < IT; ++ii) {
        const float4* rp = &pbv[(ii * 4 + ol) * RSTR];

        const float4 scv = rp[28];
        const float l2  = scv.x;
        const float s2l = scv.y;
        const float t4v = SQRT_2PI * s2l;

        float zr[P_], wr[P_];
        #pragma unroll
        for (int c = 0; c < 4; ++c) {
            const float4 z4 = rp[20 + c], w4 = rp[24 + c];
            zr[4*c+0] = z4.x; zr[4*c+1] = z4.y; zr[4*c+2] = z4.z; zr[4*c+3] = z4.w;
            wr[4*c+0] = w4.x; wr[4*c+1] = w4.y; wr[4*c+2] = w4.z; wr[4*c+3] = w4.w;
        }

        f2 xm2, xv2;
        xm2.x = xm_s[ln][ii];       xm2.y = xm_s[ln + 64][ii];
        xv2.x = xv_s[ln][ii];       xv2.y = xv_s[ln + 64][ii];
        f2 v2 = xv2 + l2;
        f2 cc2, nh2;
        cc2.x = rsqrtf(v2.x) * INV_SQRT_2PI;
        cc2.y = rsqrtf(v2.y) * INV_SQRT_2PI;
        nh2.x = -0.5f / v2.x;
        nh2.y = -0.5f / v2.y;

        // ---- pass A: all 16 em2, dm2 (parity-split chains) ----
        f2 em2[P_];
        f2 dm2a = {0.f, 0.f}, dm2b = {0.f, 0.f};
        #pragma unroll
        for (int m = 0; m < P_; ++m) {
            f2 d2 = xm2 - zr[m];
            f2 tt = d2 * d2 * nh2;
            em2[m].x = __expf(tt.x);
            em2[m].y = __expf(tt.y);
            if (m & 1) dm2b += em2[m] * wr[m];
            else       dm2a += em2[m] * wr[m];
        }
        const f2 dm2 = dm2a + dm2b;

        // ---- pass B: 20 float4 reads = 40 f16 chunks ----
        f2 u2[P_];
        #pragma unroll
        for (int tt = 0; tt < 20; ++tt) {
            const float4 F = rp[tt];
            const h2 pa = __builtin_bit_cast(h2, F.x);
            const h2 pb = __builtin_bit_cast(h2, F.y);
            const h2 pc = __builtin_bit_cast(h2, F.z);
            const h2 pd = __builtin_bit_cast(h2, F.w);
            {   // chunk 2*tt
                const int lk = 2 * tt;
                const int m = MKt[lk], c = CKt[lk];
                const float v0 = (float)pa.x, v1 = (float)pa.y;
                const float v2c = (float)pb.x, v3 = (float)pb.y;
                if (lk < 4) {
                    u2[4*c+0] = v0  * em2[m];
                    u2[4*c+1] = v1  * em2[m];
                    u2[4*c+2] = v2c * em2[m];
                    u2[4*c+3] = v3  * em2[m];
                } else {
                    u2[4*c+0] += v0  * em2[m];
                    u2[4*c+1] += v1  * em2[m];
                    u2[4*c+2] += v2c * em2[m];
                    u2[4*c+3] += v3  * em2[m];
                }
            }
            {   // chunk 2*tt+1
                const int lk = 2 * tt + 1;
                const int m = MKt[lk], c = CKt[lk];
                const float v0 = (float)pc.x, v1 = (float)pc.y;
                const float v2c = (float)pd.x, v3 = (float)pd.y;
                if (lk < 4) {
                    u2[4*c+0] = v0  * em2[m];
                    u2[4*c+1] = v1  * em2[m];
                    u2[4*c+2] = v2c * em2[m];
                    u2[4*c+3] = v3  * em2[m];
                } else {
                    u2[4*c+0] += v0  * em2[m];
                    u2[4*c+1] += v1  * em2[m];
                    u2[4*c+2] += v2c * em2[m];
                    u2[4*c+3] += v3  * em2[m];
                }
            }
        }

        f2 su2a = {0.f, 0.f}, su2b = {0.f, 0.f};
        #pragma unroll
        for (int r = 0; r < P_; r += 2) {
            su2a += u2[r] * u2[r];
            su2b += u2[r+1] * u2[r+1];
        }
        const f2 su2 = su2a + su2b;

        am2 += cc2 * dm2;
        f2 t32;
        t32.x = s2l * rsqrtf(l2 + 2.f * xv2.x);
        t32.y = s2l * rsqrtf(l2 + 2.f * xv2.y);
        av2 += t32 - t4v * (cc2 * cc2) * su2;
    }

    atomicAdd(out + ln * O_ + o,                  am2.x);
    atomicAdd(out + (ln + 64) * O_ + o,           am2.y);
    atomicAdd(out + N_ * O_ + ln * O_ + o,        av2.x);
    atomicAdd(out + N_ * O_ + (ln + 64) * O_ + o, av2.y);
}

extern "C" void kernel_launch(void* const* d_in, const int* in_sizes, int n_in,
                              void* d_out, int out_size, void* d_ws, size_t ws_size,
                              hipStream_t stream) {
    const float* x_mean = (const float*)d_in[0];
    const float* x_var  = (const float*)d_in[1];
    const float* z_param = (const float*)d_in[2];
    const float* h       = (const float*)d_in[3];
    const float* l_param = (const float*)d_in[4];
    const float* s_param = (const float*)d_in[5];
    const float* jitter_param = (const float*)d_in[6];
    float* out = (float*)d_out;

    hipMemsetAsync(d_out, 0, (size_t)out_size * sizeof(float), stream);
    gp_all<<<dim3(2048), dim3(256), 0, stream>>>(
        x_mean, x_var, z_param, h, l_param, s_param, jitter_param, out);
}

// Round 12
// 210.514 us; speedup vs baseline: 1.8025x; 1.1392x over previous
//
#include <hip/hip_runtime.h>
#include <math.h>

#define N_ 128
#define I_ 256
#define O_ 256
#define P_ 16
#define OT 4      // o's per block (site kernel)
#define IT 8      // i's per block (site kernel)
#define ICH 4     // fallback kernel chunking
#define SQRT_2PI 2.5066282746310002f
#define INV_SQRT_2PI 0.3989422804014327f

// ---- Packed record layout v3 (R23: M in f16, w/z/sc in f32) ----
// Per pair: 8 units of 64B (512B), interleaved per 16-pair group:
//   unit j of pair q at float offset (q>>4)*2048 + j*256 + (q&15)*16
//   units 0..4 : 40 M-chunks as f16 RN (chunk = col m, rows 4c..4c+3 =
//                4 f16 = 2 u32; 2 chunks per float4, producer order)
//   unit 5 : z f32   unit 6 : w f32   unit 7 : l2, s2l f32 + pad
#define GF 2048                    // floats per 16-pair group
#define NEED_BYTES ((size_t)4096 * GF * 4)   // 33.6 MB

#define TRI(r, c) ((r) * ((r) + 1) / 2 + (c))

typedef float f2 __attribute__((ext_vector_type(2)));
typedef _Float16 h2 __attribute__((ext_vector_type(2)));

__device__ __forceinline__ float fast_tanh(float x) {
    const float e2 = __expf(2.0f * x);
    return 1.0f - 2.0f / (e2 + 1.0f);
}

// f32x2 -> packed f16x2 (round-nearest via scalar casts)
__device__ __forceinline__ uint32_t pkh(float a, float b) {
    h2 h;
    h.x = (_Float16)a;
    h.y = (_Float16)b;
    return __builtin_bit_cast(uint32_t, h);
}

// ============================ Kernel 1: pairs ==============================
// R23/R7 exact (measured best, 208.9us total): serial per-thread Cholesky +
// inversion + w; store packs M to f16 RN; z, w, scalars stay f32.
// Structurally 1 wave/SIMD (1024 waves) — every alternative measured worse:
// shuffle (+38us), live-range diet (+12), LDS-resident (+110), 256-thread
// blocks (+1.5), fused-into-sites (+31 end-to-end).
__global__ __launch_bounds__(64, 1) void gp_pairs(
    const float* __restrict__ z_param, const float* __restrict__ h,
    const float* __restrict__ l_param, const float* __restrict__ s_param,
    const float* __restrict__ jitter_param, float* __restrict__ ws)
{
    const int q = blockIdx.x * 64 + threadIdx.x;   // pair index = i*256 + o
    const int io = q;

    const float l   = __expf(l_param[io]) + 0.2f;
    const float s   = __expf(s_param[io]) + 0.1f;
    const float jit = __expf(jitter_param[io]) + 0.01f;
    const float l2 = l * l;
    const float ninv2l2 = -0.5f / l2;
    const float cQ = INV_SQRT_2PI / l;
    const float noise = jit * jit / (s * s * l * SQRT_2PI);
    const float s2l = s * s * l;

    float zv[P_], hv[P_];
    {
        const float4* zp = (const float4*)(z_param + (size_t)io * P_);
        const float4* hp = (const float4*)(h + (size_t)io * P_);
        #pragma unroll
        for (int c = 0; c < 4; ++c) {
            const float4 z4 = zp[c], h4 = hp[c];
            zv[4*c+0] = z4.x; zv[4*c+1] = z4.y; zv[4*c+2] = z4.z; zv[4*c+3] = z4.w;
            hv[4*c+0] = h4.x; hv[4*c+1] = h4.y; hv[4*c+2] = h4.z; hv[4*c+3] = h4.w;
        }
    }
    #pragma unroll
    for (int p = 0; p < P_; ++p) zv[p] = fast_tanh(zv[p]);

    float A[136];
    #pragma unroll
    for (int r = 0; r < P_; ++r) {
        #pragma unroll
        for (int c = 0; c <= r; ++c) {
            const float d = zv[r] - zv[c];
            A[TRI(r, c)] = cQ * __expf(d * d * ninv2l2) + ((r == c) ? noise : 0.f);
        }
    }

    float dinv[P_];
    #pragma unroll
    for (int k = 0; k < P_; ++k) {
        const float Lkk = sqrtf(A[TRI(k, k)]);
        const float ik = 1.0f / Lkk;
        dinv[k] = ik;
        A[TRI(k, k)] = Lkk;
        #pragma unroll
        for (int r = k + 1; r < P_; ++r) A[TRI(r, k)] *= ik;
        #pragma unroll
        for (int c = k + 1; c < P_; ++c) {
            const float Lck = A[TRI(c, k)];
            #pragma unroll
            for (int r = c; r < P_; ++r) A[TRI(r, c)] -= A[TRI(r, k)] * Lck;
        }
    }

    #pragma unroll
    for (int j = 0; j < P_; ++j) {
        #pragma unroll
        for (int r = j + 1; r < P_; ++r) {
            float acc = A[TRI(r, j)] * dinv[j];
            #pragma unroll
            for (int k = j + 1; k < r; ++k) acc += A[TRI(r, k)] * A[TRI(k, j)];
            A[TRI(r, j)] = -dinv[r] * acc;
        }
        A[TRI(j, j)] = dinv[j];
    }

    float tv[P_], wv[P_];
    #pragma unroll
    for (int r = 0; r < P_; ++r) {
        float acc = 0.f;
        #pragma unroll
        for (int c = 0; c <= r; ++c) acc += A[TRI(r, c)] * hv[c];
        tv[r] = acc;
    }
    #pragma unroll
    for (int c = 0; c < P_; ++c) {
        float acc = 0.f;
        #pragma unroll
        for (int r = c; r < P_; ++r) acc += A[TRI(r, c)] * tv[r];
        wv[c] = acc;
    }

    // ---- store packed record v3 ----
    float4* rb = (float4*)ws + (size_t)(q >> 4) * (GF / 4) + (size_t)(q & 15) * 4;
    {
        float4 buf[4];
        uint32_t us[4];
        int ucnt = 0, f4 = 0;
        #pragma unroll
        for (int m = 0; m < P_; ++m) {
            #pragma unroll
            for (int c = (m >> 2); c < 4; ++c) {
                float vv[4];
                #pragma unroll
                for (int rr = 0; rr < 4; ++rr) {
                    const int r = 4 * c + rr;
                    vv[rr] = (r < m) ? 0.f : A[TRI(r, m)];
                }
                us[ucnt]     = pkh(vv[0], vv[1]);
                us[ucnt + 1] = pkh(vv[2], vv[3]);
                ucnt += 2;
                if (ucnt == 4) {
                    buf[f4 & 3] = make_float4(
                        __uint_as_float(us[0]), __uint_as_float(us[1]),
                        __uint_as_float(us[2]), __uint_as_float(us[3]));
                    ucnt = 0;
                    if ((f4 & 3) == 3) {
                        float4* up = rb + (size_t)(f4 >> 2) * 64;
                        up[0] = buf[0]; up[1] = buf[1]; up[2] = buf[2]; up[3] = buf[3];
                    }
                    ++f4;
                }
            }
        }
    }
    {
        float4* zp = rb + 5 * 64;
        zp[0] = make_float4(zv[ 0], zv[ 1], zv[ 2], zv[ 3]);
        zp[1] = make_float4(zv[ 4], zv[ 5], zv[ 6], zv[ 7]);
        zp[2] = make_float4(zv[ 8], zv[ 9], zv[10], zv[11]);
        zp[3] = make_float4(zv[12], zv[13], zv[14], zv[15]);
        float4* wp = rb + 6 * 64;
        wp[0] = make_float4(wv[ 0], wv[ 1], wv[ 2], wv[ 3]);
        wp[1] = make_float4(wv[ 4], wv[ 5], wv[ 6], wv[ 7]);
        wp[2] = make_float4(wv[ 8], wv[ 9], wv[10], wv[11]);
        wp[3] = make_float4(wv[12], wv[13], wv[14], wv[15]);
        float4* sp = rb + 7 * 64;
        sp[0] = make_float4(l2, s2l, 0.f, 0.f);
    }
}

// ============================ Kernel 2: sites ==============================
// R23 exact (measured 119.4us, VALU 53%, issue-saturated): LDS-staged with
// f16-compressed M (w/z f32). f16 M cut record reads/ii 52 -> 29 against
// the diagnosed per-CU LDS-issue-pipe bound.
__global__ __launch_bounds__(256, 2) void gp_sites(
    const float* __restrict__ x_mean, const float* __restrict__ x_var,
    const float* __restrict__ ws, float* __restrict__ out)
{
    __shared__ float xm_s[N_][IT + 1];
    __shared__ float xv_s[N_][IT + 1];
    __shared__ __align__(16) float4 pbv[32 * 32];   // 32 records x 512B

    const int t = threadIdx.x;
    const int b = blockIdx.x;
    const int ot = b & 63;
    const int ir = b >> 6;
    const int i0 = ir * IT;

    // stage x slice
    {
        const int n = t >> 1, qq = t & 1;
        const float4 xm4 = *(const float4*)(x_mean + n * I_ + i0 + qq * 4);
        const float4 xv4 = *(const float4*)(x_var  + n * I_ + i0 + qq * 4);
        xm_s[n][qq*4+0] = xm4.x; xm_s[n][qq*4+1] = xm4.y;
        xm_s[n][qq*4+2] = xm4.z; xm_s[n][qq*4+3] = xm4.w;
        xv_s[n][qq*4+0] = xv4.x; xv_s[n][qq*4+1] = xv4.y;
        xv_s[n][qq*4+2] = xv4.z; xv_s[n][qq*4+3] = xv4.w;
    }

    // stage all 32 records (8 i x 4 o), coalesced: exactly 1024 float4s
    {
        const int g_hi = ot >> 2;
        const int s0x4 = (ot & 3) * 16;         // s0*4 in float4 units
        const float4* wsv = (const float4*)ws;
        #pragma unroll
        for (int k = 0; k < 4; ++k) {
            const int idx = t + k * 256;
            const int run = idx >> 4;           // 0..63 = i*8 + j
            const int f4i = idx & 15;           // ol*4 + c
            const int i = run >> 3;
            const int j = run & 7;
            const int gi = (i0 + i) * 16 + g_hi;
            const float4 v = wsv[(size_t)gi * (GF / 4) + j * 64 + s0x4 + f4i];
            pbv[(i * 4 + (f4i >> 2)) * 32 + j * 4 + (f4i & 3)] = v;
        }
    }
    __syncthreads();

    f2 am2 = {0.f, 0.f};
    f2 av2 = {IT * 0.1f, IT * 0.1f};   // GLOBAL_JITTER per i

    const int ol = t >> 6;   // o_local (0..3), one per wave
    const int ln = t & 63;   // sites n = ln and ln+64
    const int o  = ot * OT + ol;

    // chunk lk -> (column m, row-quad c), producer's order (R5-verified)
    constexpr int MKt[40] = {0,0,0,0, 1,1,1,1, 2,2,2,2, 3,3,3,3,
                             4,4,4, 5,5,5, 6,6,6, 7,7,7,
                             8,8, 9,9, 10,10, 11,11, 12, 13, 14, 15};
    constexpr int CKt[40] = {0,1,2,3, 0,1,2,3, 0,1,2,3, 0,1,2,3,
                             1,2,3, 1,2,3, 1,2,3, 1,2,3,
                             2,3, 2,3, 2,3, 2,3, 3, 3, 3, 3};

    for (int ii = 0; ii < IT; ++ii) {
        const float4* rp = &pbv[(ii * 4 + ol) * 32];

        const float4 scv = rp[28];
        const float l2  = scv.x;
        const float s2l = scv.y;
        const float t4v = SQRT_2PI * s2l;

        float zr[P_], wr[P_];
        #pragma unroll
        for (int c = 0; c < 4; ++c) {
            const float4 z4 = rp[20 + c], w4 = rp[24 + c];
            zr[4*c+0] = z4.x; zr[4*c+1] = z4.y; zr[4*c+2] = z4.z; zr[4*c+3] = z4.w;
            wr[4*c+0] = w4.x; wr[4*c+1] = w4.y; wr[4*c+2] = w4.z; wr[4*c+3] = w4.w;
        }

        f2 xm2, xv2;
        xm2.x = xm_s[ln][ii];       xm2.y = xm_s[ln + 64][ii];
        xv2.x = xv_s[ln][ii];       xv2.y = xv_s[ln + 64][ii];
        f2 v2 = xv2 + l2;
        f2 cc2, nh2;
        cc2.x = rsqrtf(v2.x) * INV_SQRT_2PI;
        cc2.y = rsqrtf(v2.y) * INV_SQRT_2PI;
        nh2.x = -0.5f / v2.x;
        nh2.y = -0.5f / v2.y;

        // ---- pass A: all 16 em2, dm2 (parity-split chains) ----
        f2 em2[P_];
        f2 dm2a = {0.f, 0.f}, dm2b = {0.f, 0.f};
        #pragma unroll
        for (int m = 0; m < P_; ++m) {
            f2 d2 = xm2 - zr[m];
            f2 tt = d2 * d2 * nh2;
            em2[m].x = __expf(tt.x);
            em2[m].y = __expf(tt.y);
            if (m & 1) dm2b += em2[m] * wr[m];
            else       dm2a += em2[m] * wr[m];
        }
        const f2 dm2 = dm2a + dm2b;

        // ---- pass B: 20 float4 reads = 40 f16 chunks ----
        f2 u2[P_];
        #pragma unroll
        for (int tt = 0; tt < 20; ++tt) {
            const float4 F = rp[tt];
            const h2 pa = __builtin_bit_cast(h2, F.x);
            const h2 pb = __builtin_bit_cast(h2, F.y);
            const h2 pc = __builtin_bit_cast(h2, F.z);
            const h2 pd = __builtin_bit_cast(h2, F.w);
            {   // chunk 2*tt : values pa.x pa.y pb.x pb.y
                const int lk = 2 * tt;
                const int m = MKt[lk], c = CKt[lk];
                const float v0 = (float)pa.x, v1 = (float)pa.y;
                const float v2c = (float)pb.x, v3 = (float)pb.y;
                if (lk < 4) {
                    u2[4*c+0] = v0  * em2[m];
                    u2[4*c+1] = v1  * em2[m];
                    u2[4*c+2] = v2c * em2[m];
                    u2[4*c+3] = v3  * em2[m];
                } else {
                    u2[4*c+0] += v0  * em2[m];
                    u2[4*c+1] += v1  * em2[m];
                    u2[4*c+2] += v2c * em2[m];
                    u2[4*c+3] += v3  * em2[m];
                }
            }
            {   // chunk 2*tt+1 : values pc.x pc.y pd.x pd.y
                const int lk = 2 * tt + 1;
                const int m = MKt[lk], c = CKt[lk];
                const float v0 = (float)pc.x, v1 = (float)pc.y;
                const float v2c = (float)pd.x, v3 = (float)pd.y;
                if (lk < 4) {
                    u2[4*c+0] = v0  * em2[m];
                    u2[4*c+1] = v1  * em2[m];
                    u2[4*c+2] = v2c * em2[m];
                    u2[4*c+3] = v3  * em2[m];
                } else {
                    u2[4*c+0] += v0  * em2[m];
                    u2[4*c+1] += v1  * em2[m];
                    u2[4*c+2] += v2c * em2[m];
                    u2[4*c+3] += v3  * em2[m];
                }
            }
        }

        f2 su2a = {0.f, 0.f}, su2b = {0.f, 0.f};
        #pragma unroll
        for (int r = 0; r < P_; r += 2) {
            su2a += u2[r] * u2[r];
            su2b += u2[r+1] * u2[r+1];
        }
        const f2 su2 = su2a + su2b;

        am2 += cc2 * dm2;
        f2 t32;
        t32.x = s2l * rsqrtf(l2 + 2.f * xv2.x);
        t32.y = s2l * rsqrtf(l2 + 2.f * xv2.y);
        av2 += t32 - t4v * (cc2 * cc2) * su2;
    }

    atomicAdd(out + ln * O_ + o,                  am2.x);
    atomicAdd(out + (ln + 64) * O_ + o,           am2.y);
    atomicAdd(out + N_ * O_ + ln * O_ + o,        av2.x);
    atomicAdd(out + N_ * O_ + (ln + 64) * O_ + o, av2.y);
}

// ===================== Fallback: R5 monolithic kernel ======================
#define LSTR 20
__global__ __launch_bounds__(256, 2) void gp_fused(
    const float* __restrict__ x_mean, const float* __restrict__ x_var,
    const float* __restrict__ z_param, const float* __restrict__ h,
    const float* __restrict__ l_param, const float* __restrict__ s_param,
    const float* __restrict__ jitter_param, float* __restrict__ out)
{
    __shared__ float xm_s[N_][IT + 1];
    __shared__ float xv_s[N_][IT + 1];
    __shared__ __align__(16) float LinvT[ICH][OT][P_][LSTR];
    __shared__ __align__(16) float zS[ICH][OT][P_];
    __shared__ __align__(16) float wS[ICH][OT][P_];
    __shared__ float scS[ICH][OT][2];

    const int t = threadIdx.x;
    const int b = blockIdx.x;
    const int ot = b & 63;
    const int ir = b >> 6;
    const int o_base = ot * OT;
    const int i0 = ir * IT;

    {
        const int n = t >> 1, q = t & 1;
        const float4 xm4 = *(const float4*)(x_mean + n * I_ + i0 + q * 4);
        const float4 xv4 = *(const float4*)(x_var  + n * I_ + i0 + q * 4);
        xm_s[n][q*4+0] = xm4.x; xm_s[n][q*4+1] = xm4.y;
        xm_s[n][q*4+2] = xm4.z; xm_s[n][q*4+3] = xm4.w;
        xv_s[n][q*4+0] = xv4.x; xv_s[n][q*4+1] = xv4.y;
        xv_s[n][q*4+2] = xv4.z; xv_s[n][q*4+3] = xv4.w;
    }
    __syncthreads();

    f2 am2 = {0.f, 0.f};
    f2 av2 = {IT * 0.1f, IT * 0.1f};

    const int ol = t >> 6;
    const int ln = t & 63;
    const int g2 = t >> 4;
    const int il = g2 >> 2;
    const int g  = g2 & 3;
    const int p  = t & 15;

    for (int ii4 = 0; ii4 < IT / ICH; ++ii4) {
        {
            const int i  = i0 + ii4 * ICH + il;
            const int o  = o_base + g;
            const int io = i * O_ + o;
            const float l   = expf(l_param[io]) + 0.2f;
            const float s   = expf(s_param[io]) + 0.1f;
            const float jit = expf(jitter_param[io]) + 0.01f;
            const float l2 = l * l;
            const float inv2l2 = 0.5f / l2;
            const float cQ = INV_SQRT_2PI / l;
            const float noise = jit * jit / (s * s * l * SQRT_2PI);
            const float zp = tanhf(z_param[io * P_ + p]);

            float a[P_];
            #pragma unroll
            for (int c = 0; c < P_; ++c) {
                const float zc = __shfl(zp, c, P_);
                const float d = zp - zc;
                a[c] = cQ * __expf(-d * d * inv2l2) + ((c == p) ? noise : 0.0f);
            }
            #pragma unroll
            for (int k = 0; k < P_; ++k) {
                const float akk = __shfl(a[k], k, P_);
                const float lkk = sqrtf(akk);
                const float inv_lkk = 1.0f / lkk;
                if (p == k)      a[k] = lkk;
                else if (p > k)  a[k] *= inv_lkk;
                const float lrk = a[k];
                #pragma unroll
                for (int c = k + 1; c < P_; ++c) {
                    const float lck = __shfl(a[k], c, P_);
                    if (p >= c) a[c] -= lrk * lck;
                }
            }
            float x[P_];
            #pragma unroll
            for (int r = 0; r < P_; ++r) {
                const float lrr = __shfl(a[r], r, P_);
                float acc = (r == p) ? 1.0f : 0.0f;
                #pragma unroll
                for (int m = 0; m < r; ++m) {
                    const float lrm = __shfl(a[m], r, P_);
                    acc -= lrm * x[m];
                }
                x[r] = acc / lrr;
            }
            const float hc = h[io * P_ + p];
            float y[P_];
            #pragma unroll
            for (int r = 0; r < P_; ++r) y[r] = x[r] * hc;
            #pragma unroll
            for (int off = 8; off >= 1; off >>= 1) {
                #pragma unroll
                for (int r = 0; r < P_; ++r) y[r] += __shfl_xor(y[r], off, P_);
            }
            float wc = 0.f;
            #pragma unroll
            for (int r = 0; r < P_; ++r) wc += x[r] * y[r];

            float4* dst = (float4*)&LinvT[il][g][p][0];
            dst[0] = make_float4(x[ 0], x[ 1], x[ 2], x[ 3]);
            dst[1] = make_float4(x[ 4], x[ 5], x[ 6], x[ 7]);
            dst[2] = make_float4(x[ 8], x[ 9], x[10], x[11]);
            dst[3] = make_float4(x[12], x[13], x[14], x[15]);
            zS[il][g][p] = zp;
            wS[il][g][p] = wc;
            if (p == 0) { scS[il][g][0] = l2; scS[il][g][1] = s * s * l; }
        }
        __syncthreads();

        #pragma unroll
        for (int il2 = 0; il2 < ICH; ++il2) {
            const int iiA = ii4 * ICH + il2;
            const float l2  = scS[il2][ol][0];
            const float s2l = scS[il2][ol][1];
            const float t4v = SQRT_2PI * s2l;
            float zr[P_], wr[P_];
            {
                const float4* zp4 = (const float4*)&zS[il2][ol][0];
                const float4* wp4 = (const float4*)&wS[il2][ol][0];
                #pragma unroll
                for (int c = 0; c < 4; ++c) {
                    const float4 z4 = zp4[c], w4 = wp4[c];
                    zr[4*c+0] = z4.x; zr[4*c+1] = z4.y; zr[4*c+2] = z4.z; zr[4*c+3] = z4.w;
                    wr[4*c+0] = w4.x; wr[4*c+1] = w4.y; wr[4*c+2] = w4.z; wr[4*c+3] = w4.w;
                }
            }
            f2 xm2, xv2;
            xm2.x = xm_s[ln][iiA];       xm2.y = xm_s[ln + 64][iiA];
            xv2.x = xv_s[ln][iiA];       xv2.y = xv_s[ln + 64][iiA];
            f2 v2 = xv2 + l2;
            f2 cc2, nh2;
            cc2.x = rsqrtf(v2.x) * INV_SQRT_2PI;
            cc2.y = rsqrtf(v2.y) * INV_SQRT_2PI;
            nh2.x = -0.5f / v2.x;
            nh2.y = -0.5f / v2.y;
            f2 dm2 = {0.f, 0.f};
            f2 u2[P_];
            #pragma unroll
            for (int m = 0; m < P_; ++m) {
                f2 d2 = xm2 - zr[m];
                f2 tt = d2 * d2 * nh2;
                f2 em2;
                em2.x = __expf(tt.x);
                em2.y = __expf(tt.y);
                dm2 += em2 * wr[m];
                const int c0 = m >> 2;
                #pragma unroll
                for (int c = 0; c < 4; ++c) {
                    if (c < c0) continue;
                    const float4 L4 = *(const float4*)&LinvT[il2][ol][m][4*c];
                    if (m == 0) {
                        u2[4*c+0] = L4.x * em2;
                        u2[4*c+1] = L4.y * em2;
                        u2[4*c+2] = L4.z * em2;
                        u2[4*c+3] = L4.w * em2;
                    } else {
                        u2[4*c+0] += L4.x * em2;
                        u2[4*c+1] += L4.y * em2;
                        u2[4*c+2] += L4.z * em2;
                        u2[4*c+3] += L4.w * em2;
                    }
                }
            }
            f2 su2 = {0.f, 0.f};
            #pragma unroll
            for (int r = 0; r < P_; ++r) su2 += u2[r] * u2[r];
            am2 += cc2 * dm2;
            f2 t32;
            t32.x = s2l * rsqrtf(l2 + 2.f * xv2.x);
            t32.y = s2l * rsqrtf(l2 + 2.f * xv2.y);
            av2 += t32 - t4v * (cc2 * cc2) * su2;
        }
        __syncthreads();
    }

    const int o = o_base + ol;
    atomicAdd(out + ln * O_ + o,                  am2.x);
    atomicAdd(out + (ln + 64) * O_ + o,           am2.y);
    atomicAdd(out + N_ * O_ + ln * O_ + o,        av2.x);
    atomicAdd(out + N_ * O_ + (ln + 64) * O_ + o, av2.y);
}

extern "C" void kernel_launch(void* const* d_in, const int* in_sizes, int n_in,
                              void* d_out, int out_size, void* d_ws, size_t ws_size,
                              hipStream_t stream) {
    const float* x_mean = (const float*)d_in[0];
    const float* x_var  = (const float*)d_in[1];
    const float* z_param = (const float*)d_in[2];
    const float* h       = (const float*)d_in[3];
    const float* l_param = (const float*)d_in[4];
    const float* s_param = (const float*)d_in[5];
    const float* jitter_param = (const float*)d_in[6];
    float* out = (float*)d_out;

    hipMemsetAsync(d_out, 0, (size_t)out_size * sizeof(float), stream);
    if (ws_size >= NEED_BYTES) {
        gp_pairs<<<dim3(1024), dim3(64), 0, stream>>>(
            z_param, h, l_param, s_param, jitter_param, (float*)d_ws);
        gp_sites<<<dim3(2048), dim3(256), 0, stream>>>(
            x_mean, x_var, (const float*)d_ws, out);
    } else {
        gp_fused<<<dim3(2048), dim3(256), 0, stream>>>(
            x_mean, x_var, z_param, h, l_param, s_param, jitter_param, out);
    }
}